// Round 3
// baseline (191.723 us; speedup 1.0000x reference)
//
#include <hip/hip_runtime.h>

// CalculateSLayer: A = adj[:,:,0]+adj[:,:,1]  (L x L, L=4096)
//   h_in  = A^T @ h   (output 0)
//   h_out = A   @ h   (output 1)
// Round 3: latency-bound fix. Grid = 256 tiles x 4 K-splits = 1024 blocks of
// 256 threads (16 waves/CU, 50% occupancy). Cross-wave reduce via LDS
// ds_add_f32 into a 10 KB buffer (was 80 KB -> 1 block/CU). K-split partials
// go to d_ws; fan-in-4 reduce kernel assembles outputs. No global atomics.

typedef _Float16 half8 __attribute__((ext_vector_type(8)));
typedef float f32x4 __attribute__((ext_vector_type(4)));

#define LL 4096
#define DD 150
#define DPAD 160
#define RPAD 162            // red row stride: 162*4B -> bank offset 8 per row-group (<=2-way, free)
#define LLDD (LL * DD)      // 614400
#define HT_BYTES (DPAD * LL * 2)

// HT[d][j] = (fp16) h[j][d], zero-padded for 150<=d<160.
__global__ __launch_bounds__(256) void prep_kernel(const float* __restrict__ h,
                                                   _Float16* __restrict__ HT) {
    const int idx = blockIdx.x * 256 + threadIdx.x;   // grid covers DPAD*LL
    const int d = idx >> 12;
    const int j = idx & (LL - 1);
    HT[idx] = (d < DD) ? (_Float16)h[(size_t)j * DD + d] : (_Float16)0.0f;
}

// h_out partials: block (rowtile, kb) computes rows i0..i0+15 over K in
// [kb*1024, kb*1024+1024). Wave w takes K subrange of 256 (8 MFMA steps).
__global__ __launch_bounds__(256) void hout_kernel(const float* __restrict__ adj,
                                                   const _Float16* __restrict__ HT,
                                                   float* __restrict__ P) {
    __shared__ float red[16][RPAD];   // 10.4 KB
    const int tid = threadIdx.x;
    const int wave = tid >> 6, lane = tid & 63;
    const int r = lane & 15, g = lane >> 4;
    const int rowtile = blockIdx.x & 255, kb = blockIdx.x >> 8;
    const int i0 = rowtile * 16;
    const int kbase = kb * 1024 + wave * 256;

    for (int e = tid; e < 16 * RPAD; e += 256) (&red[0][0])[e] = 0.f;

    f32x4 acc[10];
#pragma unroll
    for (int nt = 0; nt < 10; ++nt) acc[nt] = (f32x4){0.f, 0.f, 0.f, 0.f};

    const float* arow = adj + (size_t)(i0 + r) * (2 * LL) + (size_t)kbase * 2 + g * 16;
#pragma unroll
    for (int c = 0; c < 8; ++c) {
        const float4* ap = (const float4*)(arow + c * 64);
        const float4 q0 = ap[0], q1 = ap[1], q2 = ap[2], q3 = ap[3];
        half8 a;
        a[0] = (_Float16)(q0.x + q0.y); a[1] = (_Float16)(q0.z + q0.w);
        a[2] = (_Float16)(q1.x + q1.y); a[3] = (_Float16)(q1.z + q1.w);
        a[4] = (_Float16)(q2.x + q2.y); a[5] = (_Float16)(q2.z + q2.w);
        a[6] = (_Float16)(q3.x + q3.y); a[7] = (_Float16)(q3.z + q3.w);
#pragma unroll
        for (int nt = 0; nt < 10; ++nt) {
            const half8 b = *(const half8*)(HT + (size_t)(nt * 16 + r) * LL
                                            + kbase + c * 32 + g * 8);
            acc[nt] = __builtin_amdgcn_mfma_f32_16x16x32_f16(a, b, acc[nt], 0, 0, 0);
        }
    }
    __syncthreads();   // red zeroed by all before atomics
    // D layout: row = g*4+q, col = r (verified rounds 1-2)
#pragma unroll
    for (int nt = 0; nt < 10; ++nt)
#pragma unroll
        for (int q = 0; q < 4; ++q)
            atomicAdd(&red[g * 4 + q][nt * 16 + r], acc[nt][q]);
    __syncthreads();
    float* dst = P + (size_t)kb * LLDD + (size_t)i0 * DD;   // h_out partial, slice kb
    for (int e = tid; e < 16 * DD; e += 256) dst[e] = red[e / DD][e % DD];
}

// h_in partials: block (coltile, kb) computes cols j0..j0+15 over K (=i) in
// [kb*1024, +1024), transposing 128-row chunks through double-buffered LDS.
__global__ __launch_bounds__(256) void hin_kernel(const float* __restrict__ adj,
                                                  const _Float16* __restrict__ HT,
                                                  float* __restrict__ P) {
    __shared__ _Float16 Tt[2][16][136];   // 8.7 KB; 136-half row stride (272 B)
    __shared__ float red[16][RPAD];       // 10.4 KB
    const int tid = threadIdx.x;
    const int wave = tid >> 6, lane = tid & 63;
    const int r = lane & 15, g = lane >> 4;
    const int coltile = blockIdx.x & 255, kb = blockIdx.x >> 8;
    const int j0 = coltile * 16;
    const int kstart = kb * 1024;
    const int lrow = tid >> 1, lhalf = tid & 1;

    for (int e = tid; e < 16 * RPAD; e += 256) (&red[0][0])[e] = 0.f;

    f32x4 acc[10];
#pragma unroll
    for (int nt = 0; nt < 10; ++nt) acc[nt] = (f32x4){0.f, 0.f, 0.f, 0.f};

    const float* abase = adj + (size_t)j0 * 2 + lhalf * 16;
    float4 q0, q1, q2, q3;
    {   // prologue: stage chunk 0
        const float4* ap = (const float4*)(abase + (size_t)(kstart + lrow) * (2 * LL));
        q0 = ap[0]; q1 = ap[1]; q2 = ap[2]; q3 = ap[3];
        _Float16 s[8] = {(_Float16)(q0.x + q0.y), (_Float16)(q0.z + q0.w),
                         (_Float16)(q1.x + q1.y), (_Float16)(q1.z + q1.w),
                         (_Float16)(q2.x + q2.y), (_Float16)(q2.z + q2.w),
                         (_Float16)(q3.x + q3.y), (_Float16)(q3.z + q3.w)};
#pragma unroll
        for (int jj = 0; jj < 8; ++jj) Tt[0][lhalf * 8 + jj][lrow] = s[jj];
    }
#pragma unroll
    for (int c = 0; c < 8; ++c) {
        __syncthreads();   // Tt[c&1] ready; prior reads of Tt[(c+1)&1] complete
        if (c < 7) {
            const float4* ap = (const float4*)(abase
                               + (size_t)(kstart + (c + 1) * 128 + lrow) * (2 * LL));
            q0 = ap[0]; q1 = ap[1]; q2 = ap[2]; q3 = ap[3];
        }
        const int buf = c & 1;
        const half8 a = *(const half8*)(&Tt[buf][r][wave * 32 + g * 8]);
#pragma unroll
        for (int nt = 0; nt < 10; ++nt) {
            const half8 b = *(const half8*)(HT + (size_t)(nt * 16 + r) * LL
                                            + kstart + c * 128 + wave * 32 + g * 8);
            acc[nt] = __builtin_amdgcn_mfma_f32_16x16x32_f16(a, b, acc[nt], 0, 0, 0);
        }
        if (c < 7) {
            _Float16 s[8] = {(_Float16)(q0.x + q0.y), (_Float16)(q0.z + q0.w),
                             (_Float16)(q1.x + q1.y), (_Float16)(q1.z + q1.w),
                             (_Float16)(q2.x + q2.y), (_Float16)(q2.z + q2.w),
                             (_Float16)(q3.x + q3.y), (_Float16)(q3.z + q3.w)};
#pragma unroll
            for (int jj = 0; jj < 8; ++jj) Tt[buf ^ 1][lhalf * 8 + jj][lrow] = s[jj];
        }
    }
    __syncthreads();
#pragma unroll
    for (int nt = 0; nt < 10; ++nt)
#pragma unroll
        for (int q = 0; q < 4; ++q)
            atomicAdd(&red[g * 4 + q][nt * 16 + r], acc[nt][q]);
    __syncthreads();
    float* dst = P + (size_t)(4 + kb) * LLDD + (size_t)j0 * DD;   // h_in partial, slice kb
    for (int e = tid; e < 16 * DD; e += 256) dst[e] = red[e / DD][e % DD];
}

// out[0:LLDD) = h_in = sum_kb P[4+kb]; out[LLDD:2*LLDD) = h_out = sum_kb P[kb]
__global__ __launch_bounds__(256) void reduce_kernel(const float* __restrict__ P,
                                                     float* __restrict__ out) {
    const int idx = blockIdx.x * 256 + threadIdx.x;   // over 2*LLDD/4 float4s
    const int nv = LLDD / 4;                          // 153600
    const float4* p = (const float4*)P;
    const float4* src = (idx < nv) ? (p + (size_t)4 * nv) : p;   // h_in : h_out
    const int e = (idx < nv) ? idx : idx - nv;
    const float4 a = src[e], b = src[e + nv], c = src[e + 2 * nv], d = src[e + 3 * nv];
    float4 s;
    s.x = (a.x + b.x) + (c.x + d.x);
    s.y = (a.y + b.y) + (c.y + d.y);
    s.z = (a.z + b.z) + (c.z + d.z);
    s.w = (a.w + b.w) + (c.w + d.w);
    ((float4*)out)[idx] = s;
}

extern "C" void kernel_launch(void* const* d_in, const int* in_sizes, int n_in,
                              void* d_out, int out_size, void* d_ws, size_t ws_size,
                              hipStream_t stream) {
    const float* adj = (const float*)d_in[0];   // [4096, 4096, 2] fp32
    const float* h   = (const float*)d_in[1];   // [4096, 150] fp32
    float* out = (float*)d_out;                  // [h_in | h_out] fp32
    _Float16* HT = (_Float16*)d_ws;              // [160][4096] fp16
    float* P = (float*)((char*)d_ws + HT_BYTES); // [8][LLDD] fp32 partials (19.7 MB)

    hipLaunchKernelGGL(prep_kernel, dim3((DPAD * LL) / 256), dim3(256), 0, stream, h, HT);
    hipLaunchKernelGGL(hout_kernel, dim3(1024), dim3(256), 0, stream, adj, HT, P);
    hipLaunchKernelGGL(hin_kernel,  dim3(1024), dim3(256), 0, stream, adj, HT, P);
    hipLaunchKernelGGL(reduce_kernel, dim3(2 * LLDD / 4 / 256), dim3(256), 0, stream, P, out);
}

// Round 4
// 127.372 us; speedup vs baseline: 1.5052x; 1.5052x over previous
//
#include <hip/hip_runtime.h>

// CalculateSLayer: A = adj[:,:,0]+adj[:,:,1]  (L x L, L=4096)
//   h_in  = A^T @ h   (output 0)
//   h_out = A   @ h   (output 1)
// Round 4: coalesced global->LDS staging restored (round-3's uncoalesced
// 16-row-scatter A loads were the BW killer). 1024 blocks (256 tiles x 4
// K-slices) of 256 threads; double-buffered 16x256 fp16 LDS tile; waves split
// the 10 d-tiles (no cross-wave reduce); K-slice partials to d_ws + fan-in-4
// reduce kernel. No global atomics.

typedef _Float16 half8 __attribute__((ext_vector_type(8)));
typedef float f32x4 __attribute__((ext_vector_type(4)));

#define LL 4096
#define DD 150
#define DPAD 160
#define TSTR 264            // halfs per LDS tile row (528 B -> +4 banks/row, <=2-way)
#define LLDD (LL * DD)      // 614400
#define HT_BYTES (DPAD * LL * 2)

// HT[d][j] = (fp16) h[j][d], zero-padded for 150<=d<160.
__global__ __launch_bounds__(256) void prep_kernel(const float* __restrict__ h,
                                                   _Float16* __restrict__ HT) {
    const int idx = blockIdx.x * 256 + threadIdx.x;   // grid covers DPAD*LL
    const int d = idx >> 12;
    const int j = idx & (LL - 1);
    HT[idx] = (d < DD) ? (_Float16)h[(size_t)j * DD + d] : (_Float16)0.0f;
}

// h_out partials: block (rowtile, kb) computes rows i0..i0+15 over K in
// [kb*1024, +1024), staged in 4 double-buffered 16x256 chunks.
// Wave w computes d-tiles {w, w+4, w+8(if w<2)} over the full block K.
__global__ __launch_bounds__(256, 4) void hout_kernel(const float* __restrict__ adj,
                                                      const _Float16* __restrict__ HT,
                                                      float* __restrict__ P) {
    __shared__ _Float16 T[2][16][TSTR];
    const int tid = threadIdx.x;
    const int wave = tid >> 6, lane = tid & 63;
    const int r = lane & 15, g = lane >> 4;
    const int rowtile = blockIdx.x & 255, kb = blockIdx.x >> 8;
    const int i0 = rowtile * 16;
    const int kstart = kb * 1024;
    const int nnt = (wave < 2) ? 3 : 2;

    const float4* adj4 = (const float4*)adj;
    f32x4 acc[3];
#pragma unroll
    for (int q = 0; q < 3; ++q) acc[q] = (f32x4){0.f, 0.f, 0.f, 0.f};

    float4 st[8];
    // prologue: load chunk 0 (contiguous 4 KB per instruction), stage to buf 0
#pragma unroll
    for (int i = 0; i < 8; ++i) {
        const int v4 = i * 256 + tid, row = v4 >> 7, o = v4 & 127;
        st[i] = adj4[(size_t)(i0 + row) * 2048 + (size_t)kstart / 2 + o];
    }
#pragma unroll
    for (int i = 0; i < 8; ++i) {
        const int v4 = i * 256 + tid, row = v4 >> 7, o = v4 & 127;
        union { _Float16 h[2]; unsigned u; } p;
        p.h[0] = (_Float16)(st[i].x + st[i].y);
        p.h[1] = (_Float16)(st[i].z + st[i].w);
        *(unsigned*)((char*)&T[0][row][0] + o * 4) = p.u;
    }
#pragma unroll
    for (int c = 0; c < 4; ++c) {
        if (c < 3) {   // issue next-chunk loads early; latency hides under MFMA
#pragma unroll
            for (int i = 0; i < 8; ++i) {
                const int v4 = i * 256 + tid, row = v4 >> 7, o = v4 & 127;
                st[i] = adj4[(size_t)(i0 + row) * 2048
                             + (size_t)(kstart + (c + 1) * 256) / 2 + o];
            }
        }
        __syncthreads();           // buf[c&1] staged by all waves
        const int buf = c & 1;
#pragma unroll
        for (int ks = 0; ks < 8; ++ks) {
            const half8 a = *(const half8*)((const char*)&T[buf][r][0] + ks * 64 + g * 16);
#pragma unroll
            for (int q = 0; q < 3; ++q) {
                if (q < nnt) {
                    const int nt = wave + q * 4;
                    const half8 b = *(const half8*)(HT + (size_t)(nt * 16 + r) * LL
                                                    + kstart + c * 256 + ks * 32 + g * 8);
                    acc[q] = __builtin_amdgcn_mfma_f32_16x16x32_f16(a, b, acc[q], 0, 0, 0);
                }
            }
        }
        if (c < 3) {   // write next buf; prior reads of it finished before the barrier
            const int nb = buf ^ 1;
#pragma unroll
            for (int i = 0; i < 8; ++i) {
                const int v4 = i * 256 + tid, row = v4 >> 7, o = v4 & 127;
                union { _Float16 h[2]; unsigned u; } p;
                p.h[0] = (_Float16)(st[i].x + st[i].y);
                p.h[1] = (_Float16)(st[i].z + st[i].w);
                *(unsigned*)((char*)&T[nb][row][0] + o * 4) = p.u;
            }
        }
    }
    // D layout: row = g*4+u, col = r (verified rounds 1-3)
#pragma unroll
    for (int q = 0; q < 3; ++q) {
        if (q < nnt) {
            const int d = (wave + q * 4) * 16 + r;
            if (d < DD) {
#pragma unroll
                for (int u = 0; u < 4; ++u)
                    P[(size_t)kb * LLDD + (size_t)(i0 + g * 4 + u) * DD + d] = acc[q][u];
            }
        }
    }
}

// h_in partials: block (coltile, kb) computes output rows j0..j0+15, reducing
// over i in [kb*1024, +1024). Column strip transposed into LDS (b32 i-pair
// writes); runs second so adj is L3-resident.
__global__ __launch_bounds__(256, 4) void hin_kernel(const float* __restrict__ adj,
                                                     const _Float16* __restrict__ HT,
                                                     float* __restrict__ P) {
    __shared__ _Float16 Tt[2][16][TSTR];   // Tt[buf][j_local][i_local 0..255]
    const int tid = threadIdx.x;
    const int wave = tid >> 6, lane = tid & 63;
    const int r = lane & 15, g = lane >> 4;
    const int coltile = blockIdx.x & 255, kb = blockIdx.x >> 8;
    const int j0 = coltile * 16;
    const int istart = kb * 1024;
    const int nnt = (wave < 2) ? 3 : 2;
    const int p2 = tid & 127;          // i-row pair index: rows 2*p2, 2*p2+1
    const int jhalf = tid >> 7;        // 0: j 0..7, 1: j 8..15
    const int j0h = j0 / 2;            // float4 offset of j0 within a row

    const float4* adj4 = (const float4*)adj;
    f32x4 acc[3];
#pragma unroll
    for (int q = 0; q < 3; ++q) acc[q] = (f32x4){0.f, 0.f, 0.f, 0.f};

    float4 sa[4], sb[4];
#pragma unroll
    for (int u = 0; u < 4; ++u) {      // prologue: chunk 0
        sa[u] = adj4[(size_t)(istart + 2 * p2) * 2048 + j0h + jhalf * 4 + u];
        sb[u] = adj4[(size_t)(istart + 2 * p2 + 1) * 2048 + j0h + jhalf * 4 + u];
    }
#pragma unroll
    for (int u = 0; u < 4; ++u) {
        const int j = jhalf * 8 + u * 2;
        union { _Float16 h[2]; unsigned w; } w0, w1;
        w0.h[0] = (_Float16)(sa[u].x + sa[u].y); w0.h[1] = (_Float16)(sb[u].x + sb[u].y);
        w1.h[0] = (_Float16)(sa[u].z + sa[u].w); w1.h[1] = (_Float16)(sb[u].z + sb[u].w);
        *(unsigned*)((char*)&Tt[0][j][0] + p2 * 4) = w0.w;
        *(unsigned*)((char*)&Tt[0][j + 1][0] + p2 * 4) = w1.w;
    }
#pragma unroll
    for (int c = 0; c < 4; ++c) {
        if (c < 3) {
            const int ib = istart + (c + 1) * 256;
#pragma unroll
            for (int u = 0; u < 4; ++u) {
                sa[u] = adj4[(size_t)(ib + 2 * p2) * 2048 + j0h + jhalf * 4 + u];
                sb[u] = adj4[(size_t)(ib + 2 * p2 + 1) * 2048 + j0h + jhalf * 4 + u];
            }
        }
        __syncthreads();
        const int buf = c & 1;
#pragma unroll
        for (int ks = 0; ks < 8; ++ks) {
            const half8 a = *(const half8*)((const char*)&Tt[buf][r][0] + ks * 64 + g * 16);
#pragma unroll
            for (int q = 0; q < 3; ++q) {
                if (q < nnt) {
                    const int nt = wave + q * 4;
                    const half8 b = *(const half8*)(HT + (size_t)(nt * 16 + r) * LL
                                                    + istart + c * 256 + ks * 32 + g * 8);
                    acc[q] = __builtin_amdgcn_mfma_f32_16x16x32_f16(a, b, acc[q], 0, 0, 0);
                }
            }
        }
        if (c < 3) {
            const int nb = buf ^ 1;
#pragma unroll
            for (int u = 0; u < 4; ++u) {
                const int j = jhalf * 8 + u * 2;
                union { _Float16 h[2]; unsigned w; } w0, w1;
                w0.h[0] = (_Float16)(sa[u].x + sa[u].y); w0.h[1] = (_Float16)(sb[u].x + sb[u].y);
                w1.h[0] = (_Float16)(sa[u].z + sa[u].w); w1.h[1] = (_Float16)(sb[u].z + sb[u].w);
                *(unsigned*)((char*)&Tt[nb][j][0] + p2 * 4) = w0.w;
                *(unsigned*)((char*)&Tt[nb][j + 1][0] + p2 * 4) = w1.w;
            }
        }
    }
#pragma unroll
    for (int q = 0; q < 3; ++q) {
        if (q < nnt) {
            const int d = (wave + q * 4) * 16 + r;
            if (d < DD) {
#pragma unroll
                for (int u = 0; u < 4; ++u)
                    P[(size_t)(4 + kb) * LLDD + (size_t)(j0 + g * 4 + u) * DD + d] = acc[q][u];
            }
        }
    }
}

// out[0:LLDD) = h_in = sum P[4..7]; out[LLDD:2*LLDD) = h_out = sum P[0..3]
__global__ __launch_bounds__(256) void reduce_kernel(const float* __restrict__ P,
                                                     float* __restrict__ out) {
    const int idx = blockIdx.x * 256 + threadIdx.x;   // over 2*LLDD/4 float4s
    const int nv = LLDD / 4;                          // 153600
    const float4* p = (const float4*)P;
    const float4* src = (idx < nv) ? (p + (size_t)4 * nv) : p;   // h_in : h_out
    const int e = (idx < nv) ? idx : idx - nv;
    const float4 a = src[e], b = src[e + nv], c = src[e + 2 * nv], d = src[e + 3 * nv];
    float4 s;
    s.x = (a.x + b.x) + (c.x + d.x);
    s.y = (a.y + b.y) + (c.y + d.y);
    s.z = (a.z + b.z) + (c.z + d.z);
    s.w = (a.w + b.w) + (c.w + d.w);
    ((float4*)out)[idx] = s;
}

extern "C" void kernel_launch(void* const* d_in, const int* in_sizes, int n_in,
                              void* d_out, int out_size, void* d_ws, size_t ws_size,
                              hipStream_t stream) {
    const float* adj = (const float*)d_in[0];   // [4096, 4096, 2] fp32
    const float* h   = (const float*)d_in[1];   // [4096, 150] fp32
    float* out = (float*)d_out;                  // [h_in | h_out] fp32
    _Float16* HT = (_Float16*)d_ws;              // [160][4096] fp16
    float* P = (float*)((char*)d_ws + HT_BYTES); // [8][LLDD] fp32 partials (19.7 MB)

    hipLaunchKernelGGL(prep_kernel, dim3((DPAD * LL) / 256), dim3(256), 0, stream, h, HT);
    hipLaunchKernelGGL(hout_kernel, dim3(1024), dim3(256), 0, stream, adj, HT, P);
    hipLaunchKernelGGL(hin_kernel,  dim3(1024), dim3(256), 0, stream, adj, HT, P);
    hipLaunchKernelGGL(reduce_kernel, dim3(2 * LLDD / 4 / 256), dim3(256), 0, stream, P, out);
}

// Round 5
// 123.195 us; speedup vs baseline: 1.5563x; 1.0339x over previous
//
#include <hip/hip_runtime.h>

// CalculateSLayer: A = adj[:,:,0]+adj[:,:,1]  (L x L, L=4096)
//   h_in  = A^T @ h   (output 0)
//   h_out = A   @ h   (output 1)
// Round 5: decouple HBM streaming from MFMA. convert_kernel streams adj once
// and emits fp16 fragment-order copies of A (AF) and A^T (ATF) into d_ws;
// gemm_kernel is barrier-free/LDS-free: waves stream MFMA-ready fragments
// sequentially from L3-resident AF/ATF, B from L2-resident HT. K-split
// partials + round-4's reduce kernel. Adaptive K-chunking if ws is small.

typedef _Float16 half8 __attribute__((ext_vector_type(8)));
typedef float f32x4 __attribute__((ext_vector_type(4)));

#define LL 4096
#define DD 150
#define DPAD 160
#define LLDD (LL * DD)                    // 614400
#define HT_BYTES ((size_t)DPAD * LL * 2)  // 1310720
#define P_BYTES ((size_t)8 * LLDD * 4)    // 19660800
#define TS 72                             // LDS tile row stride (halfs), 144 B: b128-aligned

// HT[d][j] = (fp16) h[j][d], zero-padded for 150<=d<160.
__global__ __launch_bounds__(256) void prep_kernel(const float* __restrict__ h,
                                                   _Float16* __restrict__ HT) {
    const int idx = blockIdx.x * 256 + threadIdx.x;
    const int d = idx >> 12;
    const int j = idx & (LL - 1);
    HT[idx] = (d < DD) ? (_Float16)h[(size_t)j * DD + d] : (_Float16)0.0f;
}

// Streams one 64x64 tile of A: coalesced read of adj, fp16-sum, then emits
// fragment-order units. Unit (T,S): 64 lanes x 8 halfs; lane (r=l&15,g=l>>4),
// elem e maps to A[row = T*16+r][k = S*32+g*8+e] (A-operand layout, verified
// rounds 1-4). AF tiles rows of A over k=j; ATF tiles rows of A^T (= cols of
// A) over k=i.
__global__ __launch_bounds__(256) void convert_kernel(const float* __restrict__ adj,
                                                      _Float16* __restrict__ AF,
                                                      _Float16* __restrict__ ATF,
                                                      int jbase, int nbjMask,
                                                      int nbjShift, int Ssz) {
    __shared__ _Float16 T64[64][TS];   // 9216 B
    const int tid = threadIdx.x;
    const int bi = blockIdx.x >> nbjShift;       // i-block 0..63
    const int bj = blockIdx.x & nbjMask;         // j-block within chunk
    const float4* adj4 = (const float4*)adj;
    const size_t colBase4 = (size_t)(jbase >> 1) + bj * 32;

#pragma unroll
    for (int it = 0; it < 8; ++it) {
        const int vidx = it * 256 + tid;
        const int il = vidx >> 5, jq = vidx & 31;    // row-local, float4-col
        const float4 v = adj4[(size_t)(bi * 64 + il) * 2048 + colBase4 + jq];
        union { _Float16 h[2]; unsigned u; } p;
        p.h[0] = (_Float16)(v.x + v.y);
        p.h[1] = (_Float16)(v.z + v.w);
        *(unsigned*)((char*)&T64[il][0] + jq * 4) = p.u;
    }
    __syncthreads();

    const int wave = tid >> 6, lane = tid & 63;
    const int r = lane & 15, g = lane >> 4;
#pragma unroll
    for (int c = 0; c < 2; ++c) {
        // AF: T = bi*4+wave (global i-tile), S_loc = bj*2+c (j-step in chunk)
        const half8 va = *(const half8*)((const char*)&T64[wave * 16 + r][0]
                                         + (c * 32 + g * 8) * 2);
        *(half8*)(AF + ((size_t)(bi * 4 + wave) * Ssz + (bj * 2 + c)) * 512
                  + lane * 8) = va;
        // ATF: T' = bj*4+wave (j-tile in chunk), S' = bi*2+c (i-step, global)
        half8 vt;
#pragma unroll
        for (int e = 0; e < 8; ++e) vt[e] = T64[c * 32 + g * 8 + e][wave * 16 + r];
        *(half8*)(ATF + ((size_t)(bj * 4 + wave) * 128 + (bi * 2 + c)) * 512
                  + lane * 8) = vt;
    }
}

// Barrier-free GEMM: each wave owns (output, 16-row tile, 1024-K slice).
// A-frags stream sequentially (32 KB contiguous per wave); B-frags from HT.
__global__ __launch_bounds__(256, 2) void gemm_kernel(const _Float16* __restrict__ AF,
                                                      const _Float16* __restrict__ ATF,
                                                      const _Float16* __restrict__ HT,
                                                      float* __restrict__ P,
                                                      int houtW, int Ssz, int jbase,
                                                      int chunkSL, int tlMask, int tlShift) {
    const int tid = threadIdx.x;
    const int wave = tid >> 6, lane = tid & 63;
    const int r = lane & 15, g = lane >> 4;
    const int wid = blockIdx.x * 4 + wave;

    const _Float16* fb;
    int kb, orow;
    size_t pbase;
    if (wid < houtW) {                     // h_out: rows = adj rows i, k = j
        const int T = wid & 255, sub = wid >> 8;
        fb = AF + ((size_t)T * Ssz + sub * 32) * 512;
        kb = jbase + sub * 1024;
        pbase = (size_t)(chunkSL + sub) * LLDD;
        orow = T * 16;
    } else {                               // h_in: rows = adj cols j, k = i
        const int idx = wid - houtW;
        const int Tl = idx & tlMask, sl = idx >> tlShift;
        fb = ATF + ((size_t)Tl * 128 + sl * 32) * 512;
        kb = sl * 1024;
        pbase = (size_t)(4 + sl) * LLDD;
        orow = jbase + Tl * 16;
    }

    f32x4 acc[10];
#pragma unroll
    for (int nt = 0; nt < 10; ++nt) acc[nt] = (f32x4){0.f, 0.f, 0.f, 0.f};

    const _Float16* hb = HT + (size_t)r * LL + kb + g * 8;
    const _Float16* fp = fb + lane * 8;
#pragma unroll 4
    for (int s = 0; s < 32; ++s) {
        const half8 a = *(const half8*)(fp + (size_t)s * 512);
#pragma unroll
        for (int nt = 0; nt < 10; ++nt) {
            const half8 b = *(const half8*)(hb + (size_t)nt * 16 * LL + s * 32);
            acc[nt] = __builtin_amdgcn_mfma_f32_16x16x32_f16(a, b, acc[nt], 0, 0, 0);
        }
    }
    // D layout: row = g*4+u, col = r (verified rounds 1-4)
#pragma unroll
    for (int nt = 0; nt < 10; ++nt) {
        const int d = nt * 16 + r;
        if (d < DD) {
#pragma unroll
            for (int u = 0; u < 4; ++u)
                P[pbase + (size_t)(orow + g * 4 + u) * DD + d] = acc[nt][u];
        }
    }
}

// out[0:LLDD) = h_in = sum P[4..7]; out[LLDD:2*LLDD) = h_out = sum P[0..3]
__global__ __launch_bounds__(256) void reduce_kernel(const float* __restrict__ P,
                                                     float* __restrict__ out) {
    const int idx = blockIdx.x * 256 + threadIdx.x;
    const int nv = LLDD / 4;
    const float4* p = (const float4*)P;
    const float4* src = (idx < nv) ? (p + (size_t)4 * nv) : p;
    const int e = (idx < nv) ? idx : idx - nv;
    const float4 a = src[e], b = src[e + nv], c = src[e + 2 * nv], d = src[e + 3 * nv];
    float4 s;
    s.x = (a.x + b.x) + (c.x + d.x);
    s.y = (a.y + b.y) + (c.y + d.y);
    s.z = (a.z + b.z) + (c.z + d.z);
    s.w = (a.w + b.w) + (c.w + d.w);
    ((float4*)out)[idx] = s;
}

extern "C" void kernel_launch(void* const* d_in, const int* in_sizes, int n_in,
                              void* d_out, int out_size, void* d_ws, size_t ws_size,
                              hipStream_t stream) {
    const float* adj = (const float*)d_in[0];   // [4096, 4096, 2] fp32
    const float* h   = (const float*)d_in[1];   // [4096, 150] fp32
    float* out = (float*)d_out;
    _Float16* HT = (_Float16*)d_ws;
    float* P = (float*)((char*)d_ws + HT_BYTES);
    const size_t base = HT_BYTES + P_BYTES;

    // K-chunking: frag buffers are 2 x 33.55/NCH MB; pick largest that fits.
    int NCH;
    if (ws_size >= base + 2ull * 33554432ull)      NCH = 1;
    else if (ws_size >= base + 2ull * 16777216ull) NCH = 2;
    else                                           NCH = 4;
    const size_t fragHalfs = (size_t)16777216 / NCH;
    _Float16* AF = (_Float16*)((char*)d_ws + base);
    _Float16* ATF = AF + fragHalfs;

    const int Ssz = 128 / NCH;                 // j-steps per AF tile per chunk
    const int SLn = 4 / NCH;                   // h_out P-slices per chunk
    const int nbj = 64 / NCH;                  // 64-wide j-blocks per chunk
    const int nbjShift = (NCH == 1) ? 6 : (NCH == 2) ? 5 : 4;
    const int tlShift  = (NCH == 1) ? 8 : (NCH == 2) ? 7 : 6;   // log2(256/NCH)
    const int nTi = 256 / NCH;

    hipLaunchKernelGGL(prep_kernel, dim3((DPAD * LL) / 256), dim3(256), 0, stream, h, HT);
    for (int ch = 0; ch < NCH; ++ch) {
        const int jbase = ch * (LL / NCH);
        hipLaunchKernelGGL(convert_kernel, dim3(64 * nbj), dim3(256), 0, stream,
                           adj, AF, ATF, jbase, nbj - 1, nbjShift, Ssz);
        hipLaunchKernelGGL(gemm_kernel, dim3(512 / NCH), dim3(256), 0, stream,
                           AF, ATF, HT, P, 256 * SLn, Ssz, jbase, ch * SLn,
                           nTi - 1, tlShift);
    }
    hipLaunchKernelGGL(reduce_kernel, dim3(2 * LLDD / 4 / 256), dim3(256), 0, stream,
                       P, out);
}